// Round 1
// baseline (18770.912 us; speedup 1.0000x reference)
//
#include <hip/hip_runtime.h>

#define BATCH 32

// ---------------------------------------------------------------------------
// Fused direct conv (3x3, pad=1) + optional residual + optional 1x1/s2
// shortcut conv + LIF (leaky integrate, spike, soft reset) + optional dropout
// mask + optional spike-sum accumulation.
// One thread per output element: idx -> (b, co, ho, wo), spatial innermost.
// If mem == nullptr: write raw conv result to out (used for the
// timestep-invariant conv(x, w_pre0)).
// ---------------------------------------------------------------------------
__global__ __launch_bounds__(256) void conv_lif_kernel(
    const float* __restrict__ in, const float* __restrict__ w,
    const float* __restrict__ res,                       // nullable, same shape as out
    const float* __restrict__ sc_in,                     // nullable: 1x1 stride2 pad0 shortcut input
    const float* __restrict__ sc_w,
    int scCi, int scH, int scW,
    float* __restrict__ mem,                             // nullable -> raw conv mode
    const float* __restrict__ thr_arr, const float* __restrict__ leak_arr, int layer,
    const float* __restrict__ mask,                      // nullable
    float* __restrict__ out,
    float* __restrict__ accum,                           // nullable
    int Ci, int Co, int Hin, int Win, int Hout, int Wout, int stride, int total)
{
    int idx = blockIdx.x * blockDim.x + threadIdx.x;
    if (idx >= total) return;
    int wo = idx % Wout;
    int t  = idx / Wout;
    int ho = t % Hout; t /= Hout;
    int co = t % Co;
    int b  = t / Co;

    int ih0 = ho * stride - 1;   // pad = 1
    int iw0 = wo * stride - 1;

    const float* wp = w + (size_t)co * Ci * 9;
    const float* ip = in + (size_t)b * Ci * Hin * Win;

    bool hv0 = (unsigned)(ih0)     < (unsigned)Hin;
    bool hv1 = (unsigned)(ih0 + 1) < (unsigned)Hin;
    bool hv2 = (unsigned)(ih0 + 2) < (unsigned)Hin;
    bool wv0 = (unsigned)(iw0)     < (unsigned)Win;
    bool wv1 = (unsigned)(iw0 + 1) < (unsigned)Win;
    bool wv2 = (unsigned)(iw0 + 2) < (unsigned)Win;

    float acc = 0.f;
    int plane = Hin * Win;
    for (int ci = 0; ci < Ci; ++ci) {
        const float* irow = ip + ci * plane;
        const float* wk   = wp + ci * 9;
        if (hv0) {
            const float* r = irow + ih0 * Win;
            if (wv0) acc = fmaf(r[iw0],     wk[0], acc);
            if (wv1) acc = fmaf(r[iw0 + 1], wk[1], acc);
            if (wv2) acc = fmaf(r[iw0 + 2], wk[2], acc);
        }
        if (hv1) {
            const float* r = irow + (ih0 + 1) * Win;
            if (wv0) acc = fmaf(r[iw0],     wk[3], acc);
            if (wv1) acc = fmaf(r[iw0 + 1], wk[4], acc);
            if (wv2) acc = fmaf(r[iw0 + 2], wk[5], acc);
        }
        if (hv2) {
            const float* r = irow + (ih0 + 2) * Win;
            if (wv0) acc = fmaf(r[iw0],     wk[6], acc);
            if (wv1) acc = fmaf(r[iw0 + 1], wk[7], acc);
            if (wv2) acc = fmaf(r[iw0 + 2], wk[8], acc);
        }
    }

    if (sc_in) {  // 1x1 conv, stride 2, pad 0
        int ihs = ho * 2, iws = wo * 2;
        const float* sp  = sc_in + ((size_t)b * scCi) * scH * scW + ihs * scW + iws;
        const float* swp = sc_w + (size_t)co * scCi;
        int splane = scH * scW;
        for (int c = 0; c < scCi; ++c)
            acc = fmaf(sp[(size_t)c * splane], swp[c], acc);
    }
    if (res) acc += res[idx];

    if (!mem) {            // raw conv mode (pre0 delta precompute)
        out[idx] = acc;
        return;
    }

    float thr  = thr_arr[layer];
    float leak = leak_arr[layer];
    float m    = fmaf(leak, mem[idx], acc);      // leak*mem + delta
    float mth  = m / thr - 1.0f;
    float spike = (mth > 0.f) ? 1.f : 0.f;
    mem[idx] = m - thr * spike;                  // soft reset
    float o = spike;
    if (mask) o *= mask[idx];
    out[idx] = o;
    if (accum) accum[idx] += o;
}

// Elementwise LIF for layer 0 (delta precomputed, timestep-invariant).
__global__ __launch_bounds__(256) void lif0_kernel(
    const float* __restrict__ delta, float* __restrict__ mem,
    const float* __restrict__ thr_arr, const float* __restrict__ leak_arr,
    const float* __restrict__ mask, float* __restrict__ out, int total)
{
    int idx = blockIdx.x * blockDim.x + threadIdx.x;
    if (idx >= total) return;
    float thr  = thr_arr[0];
    float leak = leak_arr[0];
    float m    = fmaf(leak, mem[idx], delta[idx]);
    float mth  = m / thr - 1.0f;
    float spike = (mth > 0.f) ? 1.f : 0.f;
    mem[idx] = m - thr * spike;
    out[idx] = spike * mask[idx];
}

// 2x2 average pool: (B,C,2H,2W) -> (B,C,H,W)
__global__ __launch_bounds__(256) void avgpool_kernel(
    const float* __restrict__ in, float* __restrict__ out,
    int C, int Hout, int Wout, int total)
{
    int idx = blockIdx.x * blockDim.x + threadIdx.x;
    if (idx >= total) return;
    int wo = idx % Wout;
    int t  = idx / Wout;
    int ho = t % Hout; t /= Hout;
    int c  = t % C;
    int b  = t / C;
    int Hin = Hout * 2, Win = Wout * 2;
    const float* p = in + (((size_t)b * C + c) * Hin + 2 * ho) * Win + 2 * wo;
    out[idx] = (p[0] + p[1] + p[Win] + p[Win + 1]) * 0.25f;
}

// FC: out[b,k] = dot(spikesum[b, :2048], wfc[k, :2048]).
// One wave (64 lanes) per (b,k); shuffle reduce.
__global__ __launch_bounds__(64) void fc_kernel(
    const float* __restrict__ s, const float* __restrict__ wfc,
    float* __restrict__ out)
{
    int bk = blockIdx.x;              // 0..319
    int b = bk / 10, k = bk % 10;
    const float* sp = s   + (size_t)b * 2048;
    const float* wp = wfc + (size_t)k * 2048;
    float acc = 0.f;
    for (int j = threadIdx.x; j < 2048; j += 64)
        acc = fmaf(sp[j], wp[j], acc);
    #pragma unroll
    for (int off = 32; off; off >>= 1)
        acc += __shfl_down(acc, off, 64);
    if (threadIdx.x == 0) out[b * 10 + k] = acc;
}

// ---------------------------------------------------------------------------
extern "C" void kernel_launch(void* const* d_in, const int* in_sizes, int n_in,
                              void* d_out, int out_size, void* d_ws, size_t ws_size,
                              hipStream_t stream) {
    const float* x      = (const float*)d_in[0];
    const float* w_pre0 = (const float*)d_in[1];
    const float* w_pre1 = (const float*)d_in[2];
    const float* w_pre2 = (const float*)d_in[3];
    const float* w1a    = (const float*)d_in[4];
    const float* w1b    = (const float*)d_in[5];
    const float* w2a    = (const float*)d_in[6];
    const float* w2b    = (const float*)d_in[7];
    const float* w2i    = (const float*)d_in[8];
    const float* w3a    = (const float*)d_in[9];
    const float* w3b    = (const float*)d_in[10];
    const float* w3i    = (const float*)d_in[11];
    const float* w4a    = (const float*)d_in[12];
    const float* w4b    = (const float*)d_in[13];
    const float* w4i    = (const float*)d_in[14];
    const float* w_fc   = (const float*)d_in[15];
    const float* thr    = (const float*)d_in[16];
    const float* leak   = (const float*)d_in[17];
    const float* mask2  = (const float*)d_in[18];
    const float* mask5  = (const float*)d_in[19];
    const float* mask9  = (const float*)d_in[20];
    const float* mask11 = (const float*)d_in[21];
    const float* mask13 = (const float*)d_in[22];
    const float* mask15 = (const float*)d_in[23];

    // ---- workspace layout (floats) ----
    float* ws = (float*)d_ws;
    size_t off = 0;
    auto alloc = [&](size_t n) { float* p = ws + off; off += n; return p; };
    // zero region: membranes + fc spike-sum
    float* m0  = alloc(2097152);  // 32*64*32*32
    float* m1  = alloc(2097152);
    float* m2  = alloc(2097152);
    float* m3  = alloc(524288);   // 32*64*16*16
    float* m4  = alloc(524288);
    float* m5  = alloc(262144);   // 32*128*8*8
    float* m6  = alloc(262144);
    float* m7  = alloc(131072);   // 32*256*4*4
    float* m8  = alloc(131072);
    float* m9  = alloc(65536);    // 32*512*2*2
    float* m10 = alloc(65536);
    float* ssum = alloc(65536);   // fc spike accumulator (32 x 2048)
    size_t zero_floats = off;
    // scratch activations
    float* delta0  = alloc(2097152);
    float* s32_a   = alloc(2097152);
    float* s32_b   = alloc(2097152);
    float* s16_inp = alloc(524288);
    float* s16_a   = alloc(524288);
    float* s16_b   = alloc(524288);
    float* s8_a    = alloc(262144);
    float* s8_b    = alloc(262144);
    float* s4_a    = alloc(131072);
    float* s4_b    = alloc(131072);
    float* s2_a    = alloc(65536);
    float* s2_b    = alloc(65536);
    (void)ws_size; (void)in_sizes; (void)n_in; (void)out_size;

    hipMemsetAsync(d_ws, 0, zero_floats * sizeof(float), stream);

    const int BLK = 256;
    auto grid = [](int total) { return dim3((total + 255) / 256); };

    // timestep-invariant: delta0 = conv(x, w_pre0)
    {
        int total = BATCH * 64 * 32 * 32;
        conv_lif_kernel<<<grid(total), BLK, 0, stream>>>(
            x, w_pre0, nullptr, nullptr, nullptr, 0, 0, 0,
            nullptr, thr, leak, 0, nullptr, delta0, nullptr,
            3, 64, 32, 32, 32, 32, 1, total);
    }

    for (int t = 0; t < 8; ++t) {
        int n32 = BATCH * 64 * 32 * 32;
        // layer 0: elementwise LIF on precomputed delta0
        lif0_kernel<<<grid(n32), BLK, 0, stream>>>(delta0, m0, thr, leak, mask2, s32_a, n32);
        // pre1: conv 64->64 @32x32 + LIF + mask5
        conv_lif_kernel<<<grid(n32), BLK, 0, stream>>>(
            s32_a, w_pre1, nullptr, nullptr, nullptr, 0, 0, 0,
            m1, thr, leak, 1, mask5, s32_b, nullptr,
            64, 64, 32, 32, 32, 32, 1, n32);
        // pre2: conv 64->64 @32x32 + LIF
        conv_lif_kernel<<<grid(n32), BLK, 0, stream>>>(
            s32_b, w_pre2, nullptr, nullptr, nullptr, 0, 0, 0,
            m2, thr, leak, 2, nullptr, s32_a, nullptr,
            64, 64, 32, 32, 32, 32, 1, n32);
        // avgpool 32x32 -> 16x16
        int n16 = BATCH * 64 * 16 * 16;
        avgpool_kernel<<<grid(n16), BLK, 0, stream>>>(s32_a, s16_inp, 64, 16, 16, n16);
        // layer1 a: conv 64->64 @16x16 + LIF + mask9
        conv_lif_kernel<<<grid(n16), BLK, 0, stream>>>(
            s16_inp, w1a, nullptr, nullptr, nullptr, 0, 0, 0,
            m3, thr, leak, 3, mask9, s16_a, nullptr,
            64, 64, 16, 16, 16, 16, 1, n16);
        // layer1 b: conv 64->64 @16x16 + identity residual + LIF
        conv_lif_kernel<<<grid(n16), BLK, 0, stream>>>(
            s16_a, w1b, s16_inp, nullptr, nullptr, 0, 0, 0,
            m4, thr, leak, 4, nullptr, s16_b, nullptr,
            64, 64, 16, 16, 16, 16, 1, n16);
        // layer2 a: conv 64->128 s2 @16->8 + LIF + mask11
        int n8 = BATCH * 128 * 8 * 8;
        conv_lif_kernel<<<grid(n8), BLK, 0, stream>>>(
            s16_b, w2a, nullptr, nullptr, nullptr, 0, 0, 0,
            m5, thr, leak, 5, mask11, s8_a, nullptr,
            64, 128, 16, 16, 8, 8, 2, n8);
        // layer2 b: conv 128->128 @8x8 + 1x1/s2 shortcut(s16_b, w2i) + LIF
        conv_lif_kernel<<<grid(n8), BLK, 0, stream>>>(
            s8_a, w2b, nullptr, s16_b, w2i, 64, 16, 16,
            m6, thr, leak, 6, nullptr, s8_b, nullptr,
            128, 128, 8, 8, 8, 8, 1, n8);
        // layer3 a: conv 128->256 s2 @8->4 + LIF + mask13
        int n4 = BATCH * 256 * 4 * 4;
        conv_lif_kernel<<<grid(n4), BLK, 0, stream>>>(
            s8_b, w3a, nullptr, nullptr, nullptr, 0, 0, 0,
            m7, thr, leak, 7, mask13, s4_a, nullptr,
            128, 256, 8, 8, 4, 4, 2, n4);
        // layer3 b: conv 256->256 @4x4 + 1x1/s2 shortcut(s8_b, w3i) + LIF
        conv_lif_kernel<<<grid(n4), BLK, 0, stream>>>(
            s4_a, w3b, nullptr, s8_b, w3i, 128, 8, 8,
            m8, thr, leak, 8, nullptr, s4_b, nullptr,
            256, 256, 4, 4, 4, 4, 1, n4);
        // layer4 a: conv 256->512 s2 @4->2 + LIF + mask15
        int n2 = BATCH * 512 * 2 * 2;
        conv_lif_kernel<<<grid(n2), BLK, 0, stream>>>(
            s4_b, w4a, nullptr, nullptr, nullptr, 0, 0, 0,
            m9, thr, leak, 9, mask15, s2_a, nullptr,
            256, 512, 4, 4, 2, 2, 2, n2);
        // layer4 b: conv 512->512 @2x2 + 1x1/s2 shortcut(s4_b, w4i) + LIF
        //           + accumulate spikes into ssum (fc is linear over timesteps)
        conv_lif_kernel<<<grid(n2), BLK, 0, stream>>>(
            s2_a, w4b, nullptr, s4_b, w4i, 256, 4, 4,
            m10, thr, leak, 10, nullptr, s2_b, ssum,
            512, 512, 2, 2, 2, 2, 1, n2);
    }

    // final FC: d_out[b,k] = dot(ssum[b], w_fc[k])
    fc_kernel<<<dim3(320), dim3(64), 0, stream>>>(ssum, w_fc, (float*)d_out);
}

// Round 2
// 7258.970 us; speedup vs baseline: 2.5859x; 2.5859x over previous
//
#include <hip/hip_runtime.h>

#define BATCH 32

// ===========================================================================
// Family 1: stride-1 3x3 conv, Ci=Co=64, square H=W (32 or 16).
// Block = 256 threads: g = tid/64 selects 4 output channels (co subgroup),
// lane = tid%64 -> (r, wq): output row r, 4-wide column quad wq.
// Each thread: 4 wo x 4 co = 16 accumulators.
// LDS: input chunk (8 ci x (ROWS+2) x (W+2), padded row stride) + weights.
// Fused epilogue: optional residual, LIF, optional dropout mask. float4 I/O.
// ===========================================================================
template<int H>
__global__ __launch_bounds__(256) void conv64_tile(
    const float* __restrict__ in, const float* __restrict__ w,
    const float* __restrict__ res,            // nullable (identity residual)
    float* __restrict__ mem,
    const float* __restrict__ thr_a, const float* __restrict__ leak_a, int layer,
    const float* __restrict__ mask,           // nullable
    float* __restrict__ out)
{
    constexpr int W    = H;
    constexpr int QR   = W / 4;               // column quads per row
    constexpr int ROWS = 64 / QR;             // rows per block tile (8 or 16)
    constexpr int RS   = W + 4;               // LDS row stride (36 or 20 -> 16B mult)
    constexpr int CC   = 8;                   // ci per chunk
    constexpr int PLANE = (ROWS + 2) * RS;
    __shared__ float sIn[CC * PLANE];         // 2880 floats for both H=32,16
    __shared__ float sW[16 * CC * 12];        // [co_l][ci][taps padded to 12]

    const int tid  = threadIdx.x;
    const int b    = blockIdx.x;
    const int rt   = blockIdx.y;              // row tile
    const int cg   = blockIdx.z;              // co group of 16
    const int lane = tid & 63;
    const int g    = tid >> 6;                // co subgroup (4 co)
    const int r    = lane / QR;               // 0..ROWS-1
    const int wq   = lane % QR;
    const int ho   = rt * ROWS + r;
    const int row0 = rt * ROWS;

    float acc[4][4] = {};
    const size_t in_b = (size_t)b * 64 * H * W;

    for (int c0 = 0; c0 < 64; c0 += CC) {
        if (c0) __syncthreads();
        // ---- stage input chunk: rows row0-1..row0+ROWS, cols -1..W ----
        constexpr int LCNT = CC * (ROWS + 2) * (W + 2);
        for (int i = tid; i < LCNT; i += 256) {
            int c   = i / ((ROWS + 2) * (W + 2));
            int rr  = (i / (W + 2)) % (ROWS + 2);
            int col = i % (W + 2);
            int ih  = row0 + rr - 1;
            int iw  = col - 1;
            float v = 0.f;
            if ((unsigned)ih < (unsigned)H && (unsigned)iw < (unsigned)W)
                v = in[in_b + (size_t)(c0 + c) * H * W + ih * W + iw];
            sIn[c * PLANE + rr * RS + col] = v;
        }
        // ---- stage weights: 16 co x CC ci x 9 taps ----
        for (int i = tid; i < 16 * CC * 9; i += 256) {
            int co_l = i / (CC * 9);
            int rem  = i % (CC * 9);
            int c    = rem / 9;
            int k    = rem % 9;
            sW[(co_l * CC + c) * 12 + k] =
                w[((size_t)(cg * 16 + co_l) * 64 + (c0 + c)) * 9 + k];
        }
        __syncthreads();

        for (int c = 0; c < CC; ++c) {
            float rv[3][6];
            #pragma unroll
            for (int dr = 0; dr < 3; ++dr) {
                const float* p = &sIn[c * PLANE + (r + dr) * RS + wq * 4];
                float4 a  = *(const float4*)p;        // cols 0..3 (16B aligned)
                float2 b2 = *(const float2*)(p + 4);  // cols 4..5
                rv[dr][0] = a.x;  rv[dr][1] = a.y; rv[dr][2] = a.z; rv[dr][3] = a.w;
                rv[dr][4] = b2.x; rv[dr][5] = b2.y;
            }
            #pragma unroll
            for (int j = 0; j < 4; ++j) {
                const float* wp = &sW[((g * 4 + j) * CC + c) * 12];
                float4 w0 = *(const float4*)wp;        // taps 0..3
                float4 w1 = *(const float4*)(wp + 4);  // taps 4..7
                float  w8 = wp[8];
                #pragma unroll
                for (int k = 0; k < 4; ++k) {
                    acc[j][k] = fmaf(rv[0][k + 0], w0.x, acc[j][k]);
                    acc[j][k] = fmaf(rv[0][k + 1], w0.y, acc[j][k]);
                    acc[j][k] = fmaf(rv[0][k + 2], w0.z, acc[j][k]);
                    acc[j][k] = fmaf(rv[1][k + 0], w0.w, acc[j][k]);
                    acc[j][k] = fmaf(rv[1][k + 1], w1.x, acc[j][k]);
                    acc[j][k] = fmaf(rv[1][k + 2], w1.y, acc[j][k]);
                    acc[j][k] = fmaf(rv[2][k + 0], w1.z, acc[j][k]);
                    acc[j][k] = fmaf(rv[2][k + 1], w1.w, acc[j][k]);
                    acc[j][k] = fmaf(rv[2][k + 2], w8,   acc[j][k]);
                }
            }
        }
    }

    // ---- fused epilogue: residual + LIF + mask, float4 I/O ----
    const float thr  = thr_a[layer];
    const float leak = leak_a[layer];
    #pragma unroll
    for (int j = 0; j < 4; ++j) {
        int co = cg * 16 + g * 4 + j;
        size_t idx = ((size_t)(b * 64 + co) * H + ho) * W + wq * 4;
        float a0 = acc[j][0], a1 = acc[j][1], a2 = acc[j][2], a3 = acc[j][3];
        if (res) {
            float4 r4 = *(const float4*)&res[idx];
            a0 += r4.x; a1 += r4.y; a2 += r4.z; a3 += r4.w;
        }
        float4 m4 = *(const float4*)&mem[idx];
        float4 k4 = mask ? *(const float4*)&mask[idx] : make_float4(1.f, 1.f, 1.f, 1.f);
        float4 mo, oo;
        {
            float m0 = fmaf(leak, m4.x, a0); float t0 = m0 / thr - 1.0f;
            float s0 = (t0 > 0.f) ? 1.f : 0.f; mo.x = m0 - thr * s0; oo.x = s0 * k4.x;
            float m1 = fmaf(leak, m4.y, a1); float t1 = m1 / thr - 1.0f;
            float s1 = (t1 > 0.f) ? 1.f : 0.f; mo.y = m1 - thr * s1; oo.y = s1 * k4.y;
            float m2 = fmaf(leak, m4.z, a2); float t2 = m2 / thr - 1.0f;
            float s2 = (t2 > 0.f) ? 1.f : 0.f; mo.z = m2 - thr * s2; oo.z = s2 * k4.z;
            float m3 = fmaf(leak, m4.w, a3); float t3 = m3 / thr - 1.0f;
            float s3 = (t3 > 0.f) ? 1.f : 0.f; mo.w = m3 - thr * s3; oo.w = s3 * k4.w;
        }
        *(float4*)&mem[idx] = mo;
        *(float4*)&out[idx] = oo;
    }
}

// ===========================================================================
// Family 2: small-spatial convs (l2-l4). 3x3 pad1 (stride 1 or 2) + optional
// fused 1x1/s2 shortcut. Entire input batch-slice staged in LDS (chunked).
// One thread per output element: tid -> (co_l, pos). Weight loads are
// wave-uniform (broadcast via L1).
// ===========================================================================
template<int CI, int HIN, int STRIDE, int CO, int SC_CI, int SC_HIN, int CHUNK>
__global__ __launch_bounds__(256) void conv_small(
    const float* __restrict__ in, const float* __restrict__ w,
    const float* __restrict__ sc_in, const float* __restrict__ sc_w,
    float* __restrict__ mem,
    const float* __restrict__ thr_a, const float* __restrict__ leak_a, int layer,
    const float* __restrict__ mask,           // nullable
    float* __restrict__ out,
    float* __restrict__ accum)                // nullable (l4b spike-sum)
{
    constexpr int HOUT = (STRIDE == 2) ? HIN / 2 : HIN;
    constexpr int NPOS = HOUT * HOUT;
    constexpr int CO_B = 256 / NPOS;
    static_assert(NPOS <= 64 && 256 % NPOS == 0, "bad NPOS");
    __shared__ float sIn[CHUNK * HIN * HIN];
    __shared__ float sSc[(SC_CI > 0) ? SC_CI * NPOS : 1];

    const int tid = threadIdx.x;
    const int b   = blockIdx.x;
    const int pos = tid % NPOS;
    const int co  = blockIdx.y * CO_B + tid / NPOS;
    const int ho  = pos / HOUT;
    const int wo  = pos % HOUT;
    const int ih0 = ho * STRIDE - 1;
    const int iw0 = wo * STRIDE - 1;
    const bool hv0 = (unsigned)(ih0)     < (unsigned)HIN;
    const bool hv1 = (unsigned)(ih0 + 1) < (unsigned)HIN;
    const bool hv2 = (unsigned)(ih0 + 2) < (unsigned)HIN;
    const bool wv0 = (unsigned)(iw0)     < (unsigned)HIN;
    const bool wv1 = (unsigned)(iw0 + 1) < (unsigned)HIN;
    const bool wv2 = (unsigned)(iw0 + 2) < (unsigned)HIN;

    const size_t in_b = (size_t)b * CI * HIN * HIN;
    float acc = 0.f;

    for (int c0 = 0; c0 < CI; c0 += CHUNK) {
        if (c0) __syncthreads();
        for (int i = tid; i < CHUNK * HIN * HIN; i += 256)
            sIn[i] = in[in_b + (size_t)c0 * HIN * HIN + i];
        if (SC_CI > 0 && c0 == 0) {
            for (int i = tid; i < SC_CI * NPOS; i += 256) {
                int ci = i / NPOS, p = i % NPOS;
                int sho = p / HOUT, swo = p % HOUT;
                sSc[i] = sc_in[((size_t)(b * SC_CI + ci) * SC_HIN + 2 * sho) * SC_HIN + 2 * swo];
            }
        }
        __syncthreads();

        for (int c = 0; c < CHUNK; ++c) {
            const float* wp = &w[((size_t)co * CI + (c0 + c)) * 9];
            float w0 = wp[0], w1 = wp[1], w2 = wp[2];
            float w3 = wp[3], w4 = wp[4], w5 = wp[5];
            float w6 = wp[6], w7 = wp[7], w8 = wp[8];
            const float* ip = &sIn[c * HIN * HIN];
            if (hv0) {
                const float* rr = ip + ih0 * HIN;
                if (wv0) acc = fmaf(rr[iw0],     w0, acc);
                if (wv1) acc = fmaf(rr[iw0 + 1], w1, acc);
                if (wv2) acc = fmaf(rr[iw0 + 2], w2, acc);
            }
            if (hv1) {
                const float* rr = ip + (ih0 + 1) * HIN;
                if (wv0) acc = fmaf(rr[iw0],     w3, acc);
                if (wv1) acc = fmaf(rr[iw0 + 1], w4, acc);
                if (wv2) acc = fmaf(rr[iw0 + 2], w5, acc);
            }
            if (hv2) {
                const float* rr = ip + (ih0 + 2) * HIN;
                if (wv0) acc = fmaf(rr[iw0],     w6, acc);
                if (wv1) acc = fmaf(rr[iw0 + 1], w7, acc);
                if (wv2) acc = fmaf(rr[iw0 + 2], w8, acc);
            }
        }
    }

    if (SC_CI > 0) {
        const float* swp = &sc_w[(size_t)co * SC_CI];
        for (int ci = 0; ci < SC_CI; ++ci)
            acc = fmaf(sSc[ci * NPOS + pos], swp[ci], acc);
    }

    const float thr  = thr_a[layer];
    const float leak = leak_a[layer];
    size_t idx = ((size_t)(b * CO + co) * HOUT + ho) * HOUT + wo;
    float m   = fmaf(leak, mem[idx], acc);
    float mth = m / thr - 1.0f;
    float sp  = (mth > 0.f) ? 1.f : 0.f;
    mem[idx]  = m - thr * sp;
    float o = sp;
    if (mask) o *= mask[idx];
    out[idx] = o;
    if (accum) accum[idx] += o;
}

// ===========================================================================
// Naive direct conv — kept ONLY for pre0 (Ci=3, runs once per launch).
// ===========================================================================
__global__ __launch_bounds__(256) void conv_raw_kernel(
    const float* __restrict__ in, const float* __restrict__ w,
    float* __restrict__ out,
    int Ci, int Co, int Hin, int Win, int total)
{
    int idx = blockIdx.x * blockDim.x + threadIdx.x;
    if (idx >= total) return;
    int wo = idx % Win;
    int t  = idx / Win;
    int ho = t % Hin; t /= Hin;
    int co = t % Co;
    int b  = t / Co;
    int ih0 = ho - 1, iw0 = wo - 1;
    const float* wp = w + (size_t)co * Ci * 9;
    const float* ip = in + (size_t)b * Ci * Hin * Win;
    bool hv0 = (unsigned)(ih0)     < (unsigned)Hin;
    bool hv1 = (unsigned)(ih0 + 1) < (unsigned)Hin;
    bool hv2 = (unsigned)(ih0 + 2) < (unsigned)Hin;
    bool wv0 = (unsigned)(iw0)     < (unsigned)Win;
    bool wv1 = (unsigned)(iw0 + 1) < (unsigned)Win;
    bool wv2 = (unsigned)(iw0 + 2) < (unsigned)Win;
    float acc = 0.f;
    int plane = Hin * Win;
    for (int ci = 0; ci < Ci; ++ci) {
        const float* irow = ip + ci * plane;
        const float* wk   = wp + ci * 9;
        if (hv0) {
            const float* r = irow + ih0 * Win;
            if (wv0) acc = fmaf(r[iw0],     wk[0], acc);
            if (wv1) acc = fmaf(r[iw0 + 1], wk[1], acc);
            if (wv2) acc = fmaf(r[iw0 + 2], wk[2], acc);
        }
        if (hv1) {
            const float* r = irow + (ih0 + 1) * Win;
            if (wv0) acc = fmaf(r[iw0],     wk[3], acc);
            if (wv1) acc = fmaf(r[iw0 + 1], wk[4], acc);
            if (wv2) acc = fmaf(r[iw0 + 2], wk[5], acc);
        }
        if (hv2) {
            const float* r = irow + (ih0 + 2) * Win;
            if (wv0) acc = fmaf(r[iw0],     wk[6], acc);
            if (wv1) acc = fmaf(r[iw0 + 1], wk[7], acc);
            if (wv2) acc = fmaf(r[iw0 + 2], wk[8], acc);
        }
    }
    out[idx] = acc;
}

// Elementwise LIF for layer 0 (delta precomputed, timestep-invariant). float4.
__global__ __launch_bounds__(256) void lif0_kernel(
    const float4* __restrict__ delta, float4* __restrict__ mem,
    const float* __restrict__ thr_a, const float* __restrict__ leak_a,
    const float4* __restrict__ mask, float4* __restrict__ out, int total4)
{
    int i = blockIdx.x * blockDim.x + threadIdx.x;
    if (i >= total4) return;
    float thr = thr_a[0], leak = leak_a[0];
    float4 d = delta[i], m4 = mem[i], k4 = mask[i], mo, oo;
    float m0 = fmaf(leak, m4.x, d.x); float s0 = (m0 / thr - 1.0f > 0.f) ? 1.f : 0.f;
    mo.x = m0 - thr * s0; oo.x = s0 * k4.x;
    float m1 = fmaf(leak, m4.y, d.y); float s1 = (m1 / thr - 1.0f > 0.f) ? 1.f : 0.f;
    mo.y = m1 - thr * s1; oo.y = s1 * k4.y;
    float m2 = fmaf(leak, m4.z, d.z); float s2 = (m2 / thr - 1.0f > 0.f) ? 1.f : 0.f;
    mo.z = m2 - thr * s2; oo.z = s2 * k4.z;
    float m3 = fmaf(leak, m4.w, d.w); float s3 = (m3 / thr - 1.0f > 0.f) ? 1.f : 0.f;
    mo.w = m3 - thr * s3; oo.w = s3 * k4.w;
    mem[i] = mo; out[i] = oo;
}

// 2x2 average pool: (B,C,2H,2W) -> (B,C,H,W)
__global__ __launch_bounds__(256) void avgpool_kernel(
    const float* __restrict__ in, float* __restrict__ out,
    int C, int Hout, int Wout, int total)
{
    int idx = blockIdx.x * blockDim.x + threadIdx.x;
    if (idx >= total) return;
    int wo = idx % Wout;
    int t  = idx / Wout;
    int ho = t % Hout; t /= Hout;
    int c  = t % C;
    int b  = t / C;
    int Hin = Hout * 2, Win = Wout * 2;
    const float* p = in + (((size_t)b * C + c) * Hin + 2 * ho) * Win + 2 * wo;
    out[idx] = (p[0] + p[1] + p[Win] + p[Win + 1]) * 0.25f;
}

// FC: out[b,k] = dot(spikesum[b, :2048], wfc[k, :2048]). One wave per (b,k).
__global__ __launch_bounds__(64) void fc_kernel(
    const float* __restrict__ s, const float* __restrict__ wfc,
    float* __restrict__ out)
{
    int bk = blockIdx.x;              // 0..319
    int b = bk / 10, k = bk % 10;
    const float* sp = s   + (size_t)b * 2048;
    const float* wp = wfc + (size_t)k * 2048;
    float acc = 0.f;
    for (int j = threadIdx.x; j < 2048; j += 64)
        acc = fmaf(sp[j], wp[j], acc);
    #pragma unroll
    for (int off = 32; off; off >>= 1)
        acc += __shfl_down(acc, off, 64);
    if (threadIdx.x == 0) out[b * 10 + k] = acc;
}

// ---------------------------------------------------------------------------
extern "C" void kernel_launch(void* const* d_in, const int* in_sizes, int n_in,
                              void* d_out, int out_size, void* d_ws, size_t ws_size,
                              hipStream_t stream) {
    const float* x      = (const float*)d_in[0];
    const float* w_pre0 = (const float*)d_in[1];
    const float* w_pre1 = (const float*)d_in[2];
    const float* w_pre2 = (const float*)d_in[3];
    const float* w1a    = (const float*)d_in[4];
    const float* w1b    = (const float*)d_in[5];
    const float* w2a    = (const float*)d_in[6];
    const float* w2b    = (const float*)d_in[7];
    const float* w2i    = (const float*)d_in[8];
    const float* w3a    = (const float*)d_in[9];
    const float* w3b    = (const float*)d_in[10];
    const float* w3i    = (const float*)d_in[11];
    const float* w4a    = (const float*)d_in[12];
    const float* w4b    = (const float*)d_in[13];
    const float* w4i    = (const float*)d_in[14];
    const float* w_fc   = (const float*)d_in[15];
    const float* thr    = (const float*)d_in[16];
    const float* leak   = (const float*)d_in[17];
    const float* mask2  = (const float*)d_in[18];
    const float* mask5  = (const float*)d_in[19];
    const float* mask9  = (const float*)d_in[20];
    const float* mask11 = (const float*)d_in[21];
    const float* mask13 = (const float*)d_in[22];
    const float* mask15 = (const float*)d_in[23];

    // ---- workspace layout (floats) ----
    float* ws = (float*)d_ws;
    size_t off = 0;
    auto alloc = [&](size_t n) { float* p = ws + off; off += n; return p; };
    float* m0  = alloc(2097152);  // 32*64*32*32
    float* m1  = alloc(2097152);
    float* m2  = alloc(2097152);
    float* m3  = alloc(524288);   // 32*64*16*16
    float* m4  = alloc(524288);
    float* m5  = alloc(262144);   // 32*128*8*8
    float* m6  = alloc(262144);
    float* m7  = alloc(131072);   // 32*256*4*4
    float* m8  = alloc(131072);
    float* m9  = alloc(65536);    // 32*512*2*2
    float* m10 = alloc(65536);
    float* ssum = alloc(65536);   // fc spike accumulator (32 x 2048)
    size_t zero_floats = off;
    float* delta0  = alloc(2097152);
    float* s32_a   = alloc(2097152);
    float* s32_b   = alloc(2097152);
    float* s16_inp = alloc(524288);
    float* s16_a   = alloc(524288);
    float* s16_b   = alloc(524288);
    float* s8_a    = alloc(262144);
    float* s8_b    = alloc(262144);
    float* s4_a    = alloc(131072);
    float* s4_b    = alloc(131072);
    float* s2_a    = alloc(65536);
    float* s2_b    = alloc(65536);
    (void)ws_size; (void)in_sizes; (void)n_in; (void)out_size;

    hipMemsetAsync(d_ws, 0, zero_floats * sizeof(float), stream);

    auto grid = [](int total) { return dim3((total + 255) / 256); };

    // timestep-invariant: delta0 = conv(x, w_pre0)
    {
        int total = BATCH * 64 * 32 * 32;
        conv_raw_kernel<<<grid(total), 256, 0, stream>>>(
            x, w_pre0, delta0, 3, 64, 32, 32, total);
    }

    for (int t = 0; t < 8; ++t) {
        int n32 = BATCH * 64 * 32 * 32;
        // layer 0: elementwise LIF on precomputed delta0
        lif0_kernel<<<grid(n32 / 4), 256, 0, stream>>>(
            (const float4*)delta0, (float4*)m0, thr, leak,
            (const float4*)mask2, (float4*)s32_a, n32 / 4);
        // pre1: 64->64 @32x32 + LIF + mask5
        conv64_tile<32><<<dim3(BATCH, 4, 4), 256, 0, stream>>>(
            s32_a, w_pre1, nullptr, m1, thr, leak, 1, mask5, s32_b);
        // pre2: 64->64 @32x32 + LIF
        conv64_tile<32><<<dim3(BATCH, 4, 4), 256, 0, stream>>>(
            s32_b, w_pre2, nullptr, m2, thr, leak, 2, nullptr, s32_a);
        // avgpool 32x32 -> 16x16
        int n16 = BATCH * 64 * 16 * 16;
        avgpool_kernel<<<grid(n16), 256, 0, stream>>>(s32_a, s16_inp, 64, 16, 16, n16);
        // layer1 a: 64->64 @16x16 + LIF + mask9
        conv64_tile<16><<<dim3(BATCH, 1, 4), 256, 0, stream>>>(
            s16_inp, w1a, nullptr, m3, thr, leak, 3, mask9, s16_a);
        // layer1 b: 64->64 @16x16 + identity residual + LIF
        conv64_tile<16><<<dim3(BATCH, 1, 4), 256, 0, stream>>>(
            s16_a, w1b, s16_inp, m4, thr, leak, 4, nullptr, s16_b);
        // layer2 a: 64->128 s2 @16->8 + LIF + mask11
        conv_small<64, 16, 2, 128, 0, 0, 32><<<dim3(BATCH, 32), 256, 0, stream>>>(
            s16_b, w2a, nullptr, nullptr, m5, thr, leak, 5, mask11, s8_a, nullptr);
        // layer2 b: 128->128 @8x8 + 1x1/s2 shortcut + LIF
        conv_small<128, 8, 1, 128, 64, 16, 128><<<dim3(BATCH, 32), 256, 0, stream>>>(
            s8_a, w2b, s16_b, w2i, m6, thr, leak, 6, nullptr, s8_b, nullptr);
        // layer3 a: 128->256 s2 @8->4 + LIF + mask13
        conv_small<128, 8, 2, 256, 0, 0, 128><<<dim3(BATCH, 16), 256, 0, stream>>>(
            s8_b, w3a, nullptr, nullptr, m7, thr, leak, 7, mask13, s4_a, nullptr);
        // layer3 b: 256->256 @4x4 + 1x1/s2 shortcut + LIF
        conv_small<256, 4, 1, 256, 128, 8, 256><<<dim3(BATCH, 16), 256, 0, stream>>>(
            s4_a, w3b, s8_b, w3i, m8, thr, leak, 8, nullptr, s4_b, nullptr);
        // layer4 a: 256->512 s2 @4->2 + LIF + mask15
        conv_small<256, 4, 2, 512, 0, 0, 256><<<dim3(BATCH, 8), 256, 0, stream>>>(
            s4_b, w4a, nullptr, nullptr, m9, thr, leak, 9, mask15, s2_a, nullptr);
        // layer4 b: 512->512 @2x2 + 1x1/s2 shortcut + LIF + spike-sum accum
        conv_small<512, 2, 1, 512, 256, 4, 512><<<dim3(BATCH, 8), 256, 0, stream>>>(
            s2_a, w4b, s4_b, w4i, m10, thr, leak, 10, nullptr, s2_b, ssum);
    }

    // final FC: d_out[b,k] = dot(ssum[b], w_fc[k])
    fc_kernel<<<dim3(320), dim3(64), 0, stream>>>(ssum, w_fc, (float*)d_out);
}

// Round 3
// 5387.588 us; speedup vs baseline: 3.4841x; 1.3474x over previous
//
#include <hip/hip_runtime.h>

#define BATCH 32

// ===========================================================================
// Family 1: stride-1 3x3 conv, Ci=Co=64, square H=W (32 or 16).
// (unchanged from round 2 — not the bottleneck per rocprof)
// ===========================================================================
template<int H>
__global__ __launch_bounds__(256) void conv64_tile(
    const float* __restrict__ in, const float* __restrict__ w,
    const float* __restrict__ res,            // nullable (identity residual)
    float* __restrict__ mem,
    const float* __restrict__ thr_a, const float* __restrict__ leak_a, int layer,
    const float* __restrict__ mask,           // nullable
    float* __restrict__ out)
{
    constexpr int W    = H;
    constexpr int QR   = W / 4;
    constexpr int ROWS = 64 / QR;
    constexpr int RS   = W + 4;
    constexpr int CC   = 8;
    constexpr int PLANE = (ROWS + 2) * RS;
    __shared__ float sIn[CC * PLANE];
    __shared__ float sW[16 * CC * 12];

    const int tid  = threadIdx.x;
    const int b    = blockIdx.x;
    const int rt   = blockIdx.y;
    const int cg   = blockIdx.z;
    const int lane = tid & 63;
    const int g    = tid >> 6;
    const int r    = lane / QR;
    const int wq   = lane % QR;
    const int ho   = rt * ROWS + r;
    const int row0 = rt * ROWS;

    float acc[4][4] = {};
    const size_t in_b = (size_t)b * 64 * H * W;

    for (int c0 = 0; c0 < 64; c0 += CC) {
        if (c0) __syncthreads();
        constexpr int LCNT = CC * (ROWS + 2) * (W + 2);
        for (int i = tid; i < LCNT; i += 256) {
            int c   = i / ((ROWS + 2) * (W + 2));
            int rr  = (i / (W + 2)) % (ROWS + 2);
            int col = i % (W + 2);
            int ih  = row0 + rr - 1;
            int iw  = col - 1;
            float v = 0.f;
            if ((unsigned)ih < (unsigned)H && (unsigned)iw < (unsigned)W)
                v = in[in_b + (size_t)(c0 + c) * H * W + ih * W + iw];
            sIn[c * PLANE + rr * RS + col] = v;
        }
        for (int i = tid; i < 16 * CC * 9; i += 256) {
            int co_l = i / (CC * 9);
            int rem  = i % (CC * 9);
            int c    = rem / 9;
            int k    = rem % 9;
            sW[(co_l * CC + c) * 12 + k] =
                w[((size_t)(cg * 16 + co_l) * 64 + (c0 + c)) * 9 + k];
        }
        __syncthreads();

        for (int c = 0; c < CC; ++c) {
            float rv[3][6];
            #pragma unroll
            for (int dr = 0; dr < 3; ++dr) {
                const float* p = &sIn[c * PLANE + (r + dr) * RS + wq * 4];
                float4 a  = *(const float4*)p;
                float2 b2 = *(const float2*)(p + 4);
                rv[dr][0] = a.x;  rv[dr][1] = a.y; rv[dr][2] = a.z; rv[dr][3] = a.w;
                rv[dr][4] = b2.x; rv[dr][5] = b2.y;
            }
            #pragma unroll
            for (int j = 0; j < 4; ++j) {
                const float* wp = &sW[((g * 4 + j) * CC + c) * 12];
                float4 w0 = *(const float4*)wp;
                float4 w1 = *(const float4*)(wp + 4);
                float  w8 = wp[8];
                #pragma unroll
                for (int k = 0; k < 4; ++k) {
                    acc[j][k] = fmaf(rv[0][k + 0], w0.x, acc[j][k]);
                    acc[j][k] = fmaf(rv[0][k + 1], w0.y, acc[j][k]);
                    acc[j][k] = fmaf(rv[0][k + 2], w0.z, acc[j][k]);
                    acc[j][k] = fmaf(rv[1][k + 0], w0.w, acc[j][k]);
                    acc[j][k] = fmaf(rv[1][k + 1], w1.x, acc[j][k]);
                    acc[j][k] = fmaf(rv[1][k + 2], w1.y, acc[j][k]);
                    acc[j][k] = fmaf(rv[2][k + 0], w1.z, acc[j][k]);
                    acc[j][k] = fmaf(rv[2][k + 1], w1.w, acc[j][k]);
                    acc[j][k] = fmaf(rv[2][k + 2], w8,   acc[j][k]);
                }
            }
        }
    }

    const float thr  = thr_a[layer];
    const float leak = leak_a[layer];
    #pragma unroll
    for (int j = 0; j < 4; ++j) {
        int co = cg * 16 + g * 4 + j;
        size_t idx = ((size_t)(b * 64 + co) * H + ho) * W + wq * 4;
        float a0 = acc[j][0], a1 = acc[j][1], a2 = acc[j][2], a3 = acc[j][3];
        if (res) {
            float4 r4 = *(const float4*)&res[idx];
            a0 += r4.x; a1 += r4.y; a2 += r4.z; a3 += r4.w;
        }
        float4 m4 = *(const float4*)&mem[idx];
        float4 k4 = mask ? *(const float4*)&mask[idx] : make_float4(1.f, 1.f, 1.f, 1.f);
        float4 mo, oo;
        {
            float m0 = fmaf(leak, m4.x, a0); float t0 = m0 / thr - 1.0f;
            float s0 = (t0 > 0.f) ? 1.f : 0.f; mo.x = m0 - thr * s0; oo.x = s0 * k4.x;
            float m1 = fmaf(leak, m4.y, a1); float t1 = m1 / thr - 1.0f;
            float s1 = (t1 > 0.f) ? 1.f : 0.f; mo.y = m1 - thr * s1; oo.y = s1 * k4.y;
            float m2 = fmaf(leak, m4.z, a2); float t2 = m2 / thr - 1.0f;
            float s2 = (t2 > 0.f) ? 1.f : 0.f; mo.z = m2 - thr * s2; oo.z = s2 * k4.z;
            float m3 = fmaf(leak, m4.w, a3); float t3 = m3 / thr - 1.0f;
            float s3 = (t3 > 0.f) ? 1.f : 0.f; mo.w = m3 - thr * s3; oo.w = s3 * k4.w;
        }
        *(float4*)&mem[idx] = mo;
        *(float4*)&out[idx] = oo;
    }
}

// ===========================================================================
// Family 2 (NEW): channel-heavy conv as wave-per-co implicit GEMM.
// A wave handles 64 outputs (b,pos) of ONE co -> weights are wave-uniform
// (readfirstlane -> s_load, scalar pipe). Input staged in LDS as zero-padded
// per-b planes (odd per-b stride -> bank-conflict-free). 3 interleaved accs.
// Block: NT threads = (NT/128) co's x 128 n's (n = b_l*P + pos).
// Optional fused 1x1/s2 shortcut (direct global reads, scalar weights) + LIF.
// ===========================================================================
template<int CI, int HIN, int STRIDE, int CO, int SC_CI, int SC_HIN,
         int CC, int NB, int NT>
__global__ __launch_bounds__(NT) void conv_cb(
    const float* __restrict__ in, const float* __restrict__ w,
    const float* __restrict__ sc_in, const float* __restrict__ sc_w,
    float* __restrict__ mem,
    const float* __restrict__ thr_a, const float* __restrict__ leak_a, int layer,
    const float* __restrict__ mask,           // nullable
    float* __restrict__ out,
    float* __restrict__ accum)                // nullable (l4b spike-sum)
{
    constexpr int HOUT = (STRIDE == 2) ? HIN / 2 : HIN;
    constexpr int P    = HOUT * HOUT;             // 64, 16 or 4
    constexpr int PW   = HIN + 2;                 // padded width
    constexpr int PP   = PW * PW;                 // padded plane (even)
    constexpr int PSTR = PP + 1;                  // odd per-b stride
    constexpr int CSTR = NB * PSTR;               // per-ci stride
    constexpr int NPIX = HIN * HIN;
    constexpr int COB  = NT / 128;                // co's per block
    static_assert(NB * P == 128, "block must cover 128 n");
    static_assert(NPIX % 4 == 0, "float4 staging");

    constexpr int SINSZ4 = (CC * CSTR + 3) / 4;
    __shared__ float4 sIn4[SINSZ4];
    float* sIn = (float*)sIn4;

    const int tid  = threadIdx.x;
    const int lane = tid & 63;
    const int col  = tid >> 7;                    // co_l (0..COB-1)
    const int nh   = (tid >> 6) & 1;              // n half
    const int n    = nh * 64 + lane;
    const int b_l  = n / P;
    const int pos  = n % P;
    const int ho   = pos / HOUT;
    const int wo   = pos % HOUT;
    const int co_u = __builtin_amdgcn_readfirstlane(blockIdx.y * COB + col);
    const int b    = blockIdx.x * NB + b_l;

    // zero whole padded LDS once; chunks only overwrite the interior
    for (int i = tid; i < SINSZ4; i += NT)
        sIn4[i] = make_float4(0.f, 0.f, 0.f, 0.f);

    const int lbase = b_l * PSTR + (ho * STRIDE) * PW + (wo * STRIDE);
    const float* wrow = w + (size_t)co_u * CI * 9;   // scalar address
    float a0 = 0.f, a1 = 0.f, a2 = 0.f;

    for (int c0 = 0; c0 < CI; c0 += CC) {
        __syncthreads();
        // stage interior: CC ci x NB b x HIN x HIN, float4 global reads
        constexpr int NF4 = CC * NB * NPIX / 4;
        for (int i = tid; i < NF4; i += NT) {
            int e   = i * 4;
            int c   = e / (NB * NPIX);
            int r   = e % (NB * NPIX);
            int bl  = r / NPIX;
            int pix = r % NPIX;
            float4 v = *(const float4*)&in[
                ((size_t)(blockIdx.x * NB + bl) * CI + (c0 + c)) * NPIX + pix];
            float vv[4] = {v.x, v.y, v.z, v.w};
            #pragma unroll
            for (int q = 0; q < 4; ++q) {
                int p  = pix + q;
                int ih = p / HIN, iw = p % HIN;
                sIn[c * CSTR + bl * PSTR + (ih + 1) * PW + (iw + 1)] = vv[q];
            }
        }
        __syncthreads();

        const float* wc = wrow + (size_t)c0 * 9;
        #pragma unroll 4
        for (int c = 0; c < CC; ++c) {
            const float* pp = &sIn[c * CSTR + lbase];
            const float* wk = wc + c * 9;
            float w0 = wk[0], w1 = wk[1], w2 = wk[2];
            float w3 = wk[3], w4 = wk[4], w5 = wk[5];
            float w6 = wk[6], w7 = wk[7], w8 = wk[8];
            a0 = fmaf(pp[0],          w0, a0);
            a1 = fmaf(pp[1],          w1, a1);
            a2 = fmaf(pp[2],          w2, a2);
            a0 = fmaf(pp[PW],         w3, a0);
            a1 = fmaf(pp[PW + 1],     w4, a1);
            a2 = fmaf(pp[PW + 2],     w5, a2);
            a0 = fmaf(pp[2 * PW],     w6, a0);
            a1 = fmaf(pp[2 * PW + 1], w7, a1);
            a2 = fmaf(pp[2 * PW + 2], w8, a2);
        }
    }

    float acc = a0 + a1 + a2;

    if constexpr (SC_CI > 0) {   // 1x1, stride 2, pad 0 shortcut
        const float* swrow = sc_w + (size_t)co_u * SC_CI;   // scalar
        const size_t sbase = (size_t)b * SC_CI * SC_HIN * SC_HIN
                           + (2 * ho) * SC_HIN + 2 * wo;
        constexpr int SPL = SC_HIN * SC_HIN;
        float s0 = 0.f, s1 = 0.f;
        #pragma unroll 4
        for (int ci = 0; ci < SC_CI; ci += 2) {
            s0 = fmaf(sc_in[sbase + (size_t)ci * SPL],       swrow[ci],     s0);
            s1 = fmaf(sc_in[sbase + (size_t)(ci + 1) * SPL], swrow[ci + 1], s1);
        }
        acc += s0 + s1;
    }

    const float thr  = thr_a[layer];
    const float leak = leak_a[layer];
    const size_t idx = (size_t)(b * CO + co_u) * P + pos;
    float m   = fmaf(leak, mem[idx], acc);
    float mth = m / thr - 1.0f;
    float sp  = (mth > 0.f) ? 1.f : 0.f;
    mem[idx]  = m - thr * sp;
    float o = sp;
    if (mask) o *= mask[idx];
    out[idx] = o;
    if (accum) accum[idx] += o;
}

// ===========================================================================
// Naive direct conv — ONLY for pre0 (Ci=3, runs once per launch).
// ===========================================================================
__global__ __launch_bounds__(256) void conv_raw_kernel(
    const float* __restrict__ in, const float* __restrict__ w,
    float* __restrict__ out,
    int Ci, int Co, int Hin, int Win, int total)
{
    int idx = blockIdx.x * blockDim.x + threadIdx.x;
    if (idx >= total) return;
    int wo = idx % Win;
    int t  = idx / Win;
    int ho = t % Hin; t /= Hin;
    int co = t % Co;
    int b  = t / Co;
    int ih0 = ho - 1, iw0 = wo - 1;
    const float* wp = w + (size_t)co * Ci * 9;
    const float* ip = in + (size_t)b * Ci * Hin * Win;
    bool hv0 = (unsigned)(ih0)     < (unsigned)Hin;
    bool hv1 = (unsigned)(ih0 + 1) < (unsigned)Hin;
    bool hv2 = (unsigned)(ih0 + 2) < (unsigned)Hin;
    bool wv0 = (unsigned)(iw0)     < (unsigned)Win;
    bool wv1 = (unsigned)(iw0 + 1) < (unsigned)Win;
    bool wv2 = (unsigned)(iw0 + 2) < (unsigned)Win;
    float acc = 0.f;
    int plane = Hin * Win;
    for (int ci = 0; ci < Ci; ++ci) {
        const float* irow = ip + ci * plane;
        const float* wk   = wp + ci * 9;
        if (hv0) {
            const float* r = irow + ih0 * Win;
            if (wv0) acc = fmaf(r[iw0],     wk[0], acc);
            if (wv1) acc = fmaf(r[iw0 + 1], wk[1], acc);
            if (wv2) acc = fmaf(r[iw0 + 2], wk[2], acc);
        }
        if (hv1) {
            const float* r = irow + (ih0 + 1) * Win;
            if (wv0) acc = fmaf(r[iw0],     wk[3], acc);
            if (wv1) acc = fmaf(r[iw0 + 1], wk[4], acc);
            if (wv2) acc = fmaf(r[iw0 + 2], wk[5], acc);
        }
        if (hv2) {
            const float* r = irow + (ih0 + 2) * Win;
            if (wv0) acc = fmaf(r[iw0],     wk[6], acc);
            if (wv1) acc = fmaf(r[iw0 + 1], wk[7], acc);
            if (wv2) acc = fmaf(r[iw0 + 2], wk[8], acc);
        }
    }
    out[idx] = acc;
}

// Elementwise LIF for layer 0 (delta precomputed, timestep-invariant). float4.
__global__ __launch_bounds__(256) void lif0_kernel(
    const float4* __restrict__ delta, float4* __restrict__ mem,
    const float* __restrict__ thr_a, const float* __restrict__ leak_a,
    const float4* __restrict__ mask, float4* __restrict__ out, int total4)
{
    int i = blockIdx.x * blockDim.x + threadIdx.x;
    if (i >= total4) return;
    float thr = thr_a[0], leak = leak_a[0];
    float4 d = delta[i], m4 = mem[i], k4 = mask[i], mo, oo;
    float m0 = fmaf(leak, m4.x, d.x); float s0 = (m0 / thr - 1.0f > 0.f) ? 1.f : 0.f;
    mo.x = m0 - thr * s0; oo.x = s0 * k4.x;
    float m1 = fmaf(leak, m4.y, d.y); float s1 = (m1 / thr - 1.0f > 0.f) ? 1.f : 0.f;
    mo.y = m1 - thr * s1; oo.y = s1 * k4.y;
    float m2 = fmaf(leak, m4.z, d.z); float s2 = (m2 / thr - 1.0f > 0.f) ? 1.f : 0.f;
    mo.z = m2 - thr * s2; oo.z = s2 * k4.z;
    float m3 = fmaf(leak, m4.w, d.w); float s3 = (m3 / thr - 1.0f > 0.f) ? 1.f : 0.f;
    mo.w = m3 - thr * s3; oo.w = s3 * k4.w;
    mem[i] = mo; out[i] = oo;
}

// 2x2 average pool: (B,C,2H,2W) -> (B,C,H,W)
__global__ __launch_bounds__(256) void avgpool_kernel(
    const float* __restrict__ in, float* __restrict__ out,
    int C, int Hout, int Wout, int total)
{
    int idx = blockIdx.x * blockDim.x + threadIdx.x;
    if (idx >= total) return;
    int wo = idx % Wout;
    int t  = idx / Wout;
    int ho = t % Hout; t /= Hout;
    int c  = t % C;
    int b  = t / C;
    int Hin = Hout * 2, Win = Wout * 2;
    const float* p = in + (((size_t)b * C + c) * Hin + 2 * ho) * Win + 2 * wo;
    out[idx] = (p[0] + p[1] + p[Win] + p[Win + 1]) * 0.25f;
}

// FC: out[b,k] = dot(spikesum[b, :2048], wfc[k, :2048]). One wave per (b,k).
__global__ __launch_bounds__(64) void fc_kernel(
    const float* __restrict__ s, const float* __restrict__ wfc,
    float* __restrict__ out)
{
    int bk = blockIdx.x;
    int b = bk / 10, k = bk % 10;
    const float* sp = s   + (size_t)b * 2048;
    const float* wp = wfc + (size_t)k * 2048;
    float acc = 0.f;
    for (int j = threadIdx.x; j < 2048; j += 64)
        acc = fmaf(sp[j], wp[j], acc);
    #pragma unroll
    for (int off = 32; off; off >>= 1)
        acc += __shfl_down(acc, off, 64);
    if (threadIdx.x == 0) out[b * 10 + k] = acc;
}

// ---------------------------------------------------------------------------
extern "C" void kernel_launch(void* const* d_in, const int* in_sizes, int n_in,
                              void* d_out, int out_size, void* d_ws, size_t ws_size,
                              hipStream_t stream) {
    const float* x      = (const float*)d_in[0];
    const float* w_pre0 = (const float*)d_in[1];
    const float* w_pre1 = (const float*)d_in[2];
    const float* w_pre2 = (const float*)d_in[3];
    const float* w1a    = (const float*)d_in[4];
    const float* w1b    = (const float*)d_in[5];
    const float* w2a    = (const float*)d_in[6];
    const float* w2b    = (const float*)d_in[7];
    const float* w2i    = (const float*)d_in[8];
    const float* w3a    = (const float*)d_in[9];
    const float* w3b    = (const float*)d_in[10];
    const float* w3i    = (const float*)d_in[11];
    const float* w4a    = (const float*)d_in[12];
    const float* w4b    = (const float*)d_in[13];
    const float* w4i    = (const float*)d_in[14];
    const float* w_fc   = (const float*)d_in[15];
    const float* thr    = (const float*)d_in[16];
    const float* leak   = (const float*)d_in[17];
    const float* mask2  = (const float*)d_in[18];
    const float* mask5  = (const float*)d_in[19];
    const float* mask9  = (const float*)d_in[20];
    const float* mask11 = (const float*)d_in[21];
    const float* mask13 = (const float*)d_in[22];
    const float* mask15 = (const float*)d_in[23];

    // ---- workspace layout (floats) ----
    float* ws = (float*)d_ws;
    size_t off = 0;
    auto alloc = [&](size_t n) { float* p = ws + off; off += n; return p; };
    float* m0  = alloc(2097152);  // 32*64*32*32
    float* m1  = alloc(2097152);
    float* m2  = alloc(2097152);
    float* m3  = alloc(524288);   // 32*64*16*16
    float* m4  = alloc(524288);
    float* m5  = alloc(262144);   // 32*128*8*8
    float* m6  = alloc(262144);
    float* m7  = alloc(131072);   // 32*256*4*4
    float* m8  = alloc(131072);
    float* m9  = alloc(65536);    // 32*512*2*2
    float* m10 = alloc(65536);
    float* ssum = alloc(65536);   // fc spike accumulator (32 x 2048)
    size_t zero_floats = off;
    float* delta0  = alloc(2097152);
    float* s32_a   = alloc(2097152);
    float* s32_b   = alloc(2097152);
    float* s16_inp = alloc(524288);
    float* s16_a   = alloc(524288);
    float* s16_b   = alloc(524288);
    float* s8_a    = alloc(262144);
    float* s8_b    = alloc(262144);
    float* s4_a    = alloc(131072);
    float* s4_b    = alloc(131072);
    float* s2_a    = alloc(65536);
    float* s2_b    = alloc(65536);
    (void)ws_size; (void)in_sizes; (void)n_in; (void)out_size;

    hipMemsetAsync(d_ws, 0, zero_floats * sizeof(float), stream);

    auto grid = [](int total) { return dim3((total + 255) / 256); };

    // timestep-invariant: delta0 = conv(x, w_pre0)
    {
        int total = BATCH * 64 * 32 * 32;
        conv_raw_kernel<<<grid(total), 256, 0, stream>>>(
            x, w_pre0, delta0, 3, 64, 32, 32, total);
    }

    for (int t = 0; t < 8; ++t) {
        int n32 = BATCH * 64 * 32 * 32;
        // layer 0: elementwise LIF on precomputed delta0
        lif0_kernel<<<grid(n32 / 4), 256, 0, stream>>>(
            (const float4*)delta0, (float4*)m0, thr, leak,
            (const float4*)mask2, (float4*)s32_a, n32 / 4);
        // pre1: 64->64 @32x32 + LIF + mask5
        conv64_tile<32><<<dim3(BATCH, 4, 4), 256, 0, stream>>>(
            s32_a, w_pre1, nullptr, m1, thr, leak, 1, mask5, s32_b);
        // pre2: 64->64 @32x32 + LIF
        conv64_tile<32><<<dim3(BATCH, 4, 4), 256, 0, stream>>>(
            s32_b, w_pre2, nullptr, m2, thr, leak, 2, nullptr, s32_a);
        // avgpool 32x32 -> 16x16
        int n16 = BATCH * 64 * 16 * 16;
        avgpool_kernel<<<grid(n16), 256, 0, stream>>>(s32_a, s16_inp, 64, 16, 16, n16);
        // layer1 a: 64->64 @16x16 + LIF + mask9
        conv64_tile<16><<<dim3(BATCH, 1, 4), 256, 0, stream>>>(
            s16_inp, w1a, nullptr, m3, thr, leak, 3, mask9, s16_a);
        // layer1 b: 64->64 @16x16 + identity residual + LIF
        conv64_tile<16><<<dim3(BATCH, 1, 4), 256, 0, stream>>>(
            s16_a, w1b, s16_inp, m4, thr, leak, 4, nullptr, s16_b);

        // layer2 a: 64->128 s2 @16->8 + LIF + mask11   (NB=2, CC=8, NT=256)
        conv_cb<64, 16, 2, 128, 0, 0, 8, 2, 256><<<dim3(16, 64), 256, 0, stream>>>(
            s16_b, w2a, nullptr, nullptr, m5, thr, leak, 5, mask11, s8_a, nullptr);
        // layer2 b: 128->128 @8x8 + 1x1/s2 shortcut + LIF
        conv_cb<128, 8, 1, 128, 64, 16, 16, 2, 256><<<dim3(16, 64), 256, 0, stream>>>(
            s8_a, w2b, s16_b, w2i, m6, thr, leak, 6, nullptr, s8_b, nullptr);
        // layer3 a: 128->256 s2 @8->4 + LIF + mask13
        conv_cb<128, 8, 2, 256, 0, 0, 8, 8, 256><<<dim3(4, 128), 256, 0, stream>>>(
            s8_b, w3a, nullptr, nullptr, m7, thr, leak, 7, mask13, s4_a, nullptr);
        // layer3 b: 256->256 @4x4 + 1x1/s2 shortcut + LIF
        conv_cb<256, 4, 1, 256, 128, 8, 16, 8, 256><<<dim3(4, 128), 256, 0, stream>>>(
            s4_a, w3b, s8_b, w3i, m8, thr, leak, 8, nullptr, s4_b, nullptr);
        // layer4 a: 256->512 s2 @4->2 + LIF + mask15   (NT=128: 1 co/block)
        conv_cb<256, 4, 2, 512, 0, 0, 8, 32, 128><<<dim3(1, 512), 128, 0, stream>>>(
            s4_b, w4a, nullptr, nullptr, m9, thr, leak, 9, mask15, s2_a, nullptr);
        // layer4 b: 512->512 @2x2 + 1x1/s2 shortcut + LIF + spike-sum accum
        conv_cb<512, 2, 1, 512, 256, 4, 16, 32, 128><<<dim3(1, 512), 128, 0, stream>>>(
            s2_a, w4b, s4_b, w4i, m10, thr, leak, 10, nullptr, s2_b, ssum);
    }

    // final FC: d_out[b,k] = dot(ssum[b], w_fc[k])
    fc_kernel<<<dim3(320), dim3(64), 0, stream>>>(ssum, w_fc, (float*)d_out);
}